// Round 2
// baseline (871.285 us; speedup 1.0000x reference)
//
#include <hip/hip_runtime.h>
#include <hip/hip_fp16.h>

typedef _Float16 f16x8 __attribute__((ext_vector_type(8)));
typedef float    f32x4 __attribute__((ext_vector_type(4)));

#define NS      2048
#define BSZ     4
#define DD      256
#define EPSV    0.1f
#define INVE    10.0f
#define TINYV   1e-8f
#define THRESHV 0.1f
#define NROWS   (BSZ*NS)               /* 8192 */
#define NELEM   ((size_t)BSZ*NS*NS)    /* 16777216 */
#define NSLICE  8
#define ZWORDS  (8192+8192+NSLICE*8192+400+101+1)   /* u,v,colsum,errbuf,done,cmax */

// ---------------- prep: fp16 casts of x,y + row sq-norms + ws zeroing ----------------
__global__ __launch_bounds__(256) void prep_kernel(
    const float* __restrict__ x, const float* __restrict__ y,
    __half* __restrict__ xh, __half* __restrict__ yh,
    float* __restrict__ x2, float* __restrict__ y2,
    float* __restrict__ wszero, float* __restrict__ cost)
{
  const int gtid = blockIdx.x * 256 + threadIdx.x;
  const int row  = blockIdx.x * 4 + (threadIdx.x >> 6);
  const int lane = threadIdx.x & 63;
  const float* src; __half* dst; float* ssum;
  if (row < NROWS) { src = x + ((size_t)row*DD); dst = xh + ((size_t)row*DD); ssum = x2 + row; }
  else { const int r2 = row - NROWS; src = y + ((size_t)r2*DD); dst = yh + ((size_t)r2*DD); ssum = y2 + r2; }
  const float4 vx = *(const float4*)(src + lane*4);
  float sq = vx.x*vx.x + vx.y*vx.y + vx.z*vx.z + vx.w*vx.w;
  union { _Float16 h[4]; uint2 u2; } cvt;
  cvt.h[0] = (_Float16)vx.x; cvt.h[1] = (_Float16)vx.y;
  cvt.h[2] = (_Float16)vx.z; cvt.h[3] = (_Float16)vx.w;
  *(uint2*)(dst + lane*4) = cvt.u2;
  #pragma unroll
  for (int off = 32; off; off >>= 1) sq += __shfl_xor(sq, off);
  if (lane == 0) *ssum = sq;
  if (gtid < ZWORDS) wszero[gtid] = 0.0f;   // zeros u,v,colsum,errbuf,done,cmax
  if (gtid < 4) cost[gtid] = 0.0f;
}

// ---------------- GEMM: C = x2_i + y2_j - 2*x.y  (fp16 out) + global max ----------------
__global__ __launch_bounds__(256) void gemm_cost_kernel(
    const __half* __restrict__ xh, const __half* __restrict__ yh,
    const float* __restrict__ x2, const float* __restrict__ y2,
    __half* __restrict__ Ch, unsigned int* __restrict__ cmax)
{
  const int b  = blockIdx.z;
  const int j0 = blockIdx.x * 128;
  const int i0 = blockIdx.y * 128;
  const int tid  = threadIdx.x;
  const int lane = tid & 63;
  const int wid  = tid >> 6;
  const int wr = wid >> 1, wc = wid & 1;

  __shared__ _Float16 As[128][40];
  __shared__ _Float16 Bs[128][40];

  f32x4 acc[4][4];
  #pragma unroll
  for (int m = 0; m < 4; m++)
    #pragma unroll
    for (int n = 0; n < 4; n++) acc[m][n] = (f32x4)0.0f;

  const size_t xbase = ((size_t)b*NS + i0) * DD;
  const size_t ybase = ((size_t)b*NS + j0) * DD;
  const int ldrow = tid >> 1;
  const int ldseg = (tid & 1) * 16;

  for (int k0 = 0; k0 < DD; k0 += 32) {
    __syncthreads();
    const __half* ax = xh + xbase + (size_t)ldrow*DD + k0 + ldseg;
    const __half* by = yh + ybase + (size_t)ldrow*DD + k0 + ldseg;
    uint4 a0 = *(const uint4*)ax;  uint4 a1 = *(const uint4*)(ax + 8);
    uint4 b0 = *(const uint4*)by;  uint4 b1 = *(const uint4*)(by + 8);
    *(uint4*)&As[ldrow][ldseg]   = a0;  *(uint4*)&As[ldrow][ldseg+8] = a1;
    *(uint4*)&Bs[ldrow][ldseg]   = b0;  *(uint4*)&Bs[ldrow][ldseg+8] = b1;
    __syncthreads();
    const int ksel = (lane >> 4) * 8;
    f16x8 afr[4], bfr[4];
    #pragma unroll
    for (int m = 0; m < 4; m++) {
      afr[m] = *(const f16x8*)&As[wr*64 + m*16 + (lane & 15)][ksel];
      bfr[m] = *(const f16x8*)&Bs[wc*64 + m*16 + (lane & 15)][ksel];
    }
    #pragma unroll
    for (int m = 0; m < 4; m++)
      #pragma unroll
      for (int n = 0; n < 4; n++)
        acc[m][n] = __builtin_amdgcn_mfma_f32_16x16x32_f16(afr[m], bfr[n], acc[m][n], 0, 0, 0);
  }

  float mx = 0.0f;
  const float* x2b = x2 + b*NS;
  const float* y2b = y2 + b*NS;
  #pragma unroll
  for (int m = 0; m < 4; m++) {
    #pragma unroll
    for (int n = 0; n < 4; n++) {
      const int col = j0 + wc*64 + n*16 + (lane & 15);
      const float y2v = y2b[col];
      #pragma unroll
      for (int q = 0; q < 4; q++) {
        const int row = i0 + wr*64 + m*16 + ((lane >> 4) * 4) + q;
        const float cval = x2b[row] + y2v - 2.0f * acc[m][n][q];
        mx = fmaxf(mx, cval);
        Ch[((size_t)b*NS + row)*NS + col] = __float2half(cval);
      }
    }
  }
  #pragma unroll
  for (int off = 32; off; off >>= 1) mx = fmaxf(mx, __shfl_xor(mx, off));
  if (lane == 0) atomicMax(cmax, __float_as_uint(mx));
}

// ---------------- per-iteration kernel 1: fused u-update + column partial sums ----------------
__global__ __launch_bounds__(256) void iter_row_kernel(
    const __half* __restrict__ Ch, float* __restrict__ u, const float* __restrict__ v,
    float* __restrict__ colsum, float* __restrict__ errbuf,
    const int* __restrict__ done, const unsigned int* __restrict__ cmax, int t)
{
  if (done[t]) return;
  const int tid = threadIdx.x;
  const int bid = blockIdx.x;
  const int r0  = bid * 8;        // 8 rows of the flattened 8192
  const int b   = bid >> 8;       // batch
  const int jt  = tid * 8;        // 8 columns per thread
  const int bcol = b << 11;
  const float scl   = 1.0f / __uint_as_float(*cmax);
  const float LOGMU = logf(1.0f/2048.0f + TINYV);
  __shared__ float red[8][4];

  float vj[8], ui[8];
  { const float4 a = *(const float4*)(v + bcol + jt);
    const float4 c = *(const float4*)(v + bcol + jt + 4);
    vj[0]=a.x; vj[1]=a.y; vj[2]=a.z; vj[3]=a.w; vj[4]=c.x; vj[5]=c.y; vj[6]=c.z; vj[7]=c.w; }
  { const float4 a = *(const float4*)(u + r0);
    const float4 c = *(const float4*)(u + r0 + 4);
    ui[0]=a.x; ui[1]=a.y; ui[2]=a.z; ui[3]=a.w; ui[4]=c.x; ui[5]=c.y; ui[6]=c.z; ui[7]=c.w; }

  f16x8 ch[8];
  #pragma unroll
  for (int rr = 0; rr < 8; ++rr) {
    ch[rr] = *(const f16x8*)(Ch + ((size_t)(r0+rr) << 11) + jt);
    float ls = 0.0f;
    #pragma unroll
    for (int k = 0; k < 8; k++)
      ls += __expf((ui[rr] + vj[k] - (float)ch[rr][k]*scl) * INVE);
    #pragma unroll
    for (int off = 32; off; off >>= 1) ls += __shfl_xor(ls, off);
    if ((tid & 63) == 0) red[rr][tid >> 6] = ls;
  }
  __syncthreads();

  float colacc[8], unew[8];
  #pragma unroll
  for (int k = 0; k < 8; k++) colacc[k] = 0.0f;
  float errloc = 0.0f;
  #pragma unroll
  for (int rr = 0; rr < 8; ++rr) {
    const float S  = (red[rr][0] + red[rr][1]) + (red[rr][2] + red[rr][3]);
    const float du = EPSV * (LOGMU - logf(TINYV + S));
    unew[rr] = ui[rr] + du;
    errloc += fabsf(du);
    #pragma unroll
    for (int k = 0; k < 8; k++)   // colsum uses u_NEW, exactly as reference
      colacc[k] += __expf((unew[rr] + vj[k] - (float)ch[rr][k]*scl) * INVE);
  }
  float* accp = colsum + (bid & (NSLICE-1)) * NROWS + bcol;
  #pragma unroll
  for (int k = 0; k < 8; k++) atomicAdd(accp + jt + k, colacc[k]);
  if (tid == 0) {
    *(float4*)(u + r0)     = make_float4(unew[0], unew[1], unew[2], unew[3]);
    *(float4*)(u + r0 + 4) = make_float4(unew[4], unew[5], unew[6], unew[7]);
    atomicAdd(errbuf + t*4 + b, errloc);
  }
}

// ---------------- per-iteration kernel 2: v update + convergence flag ----------------
__global__ __launch_bounds__(256) void col_update_kernel(
    float* __restrict__ v, float* __restrict__ colsum,
    const float* __restrict__ errbuf, int* __restrict__ done, int t)
{
  if (done[t]) {
    if (blockIdx.x == 0 && threadIdx.x == 0) done[t+1] = 1;
    return;
  }
  const int c = blockIdx.x * 256 + threadIdx.x;   // 0..8191 (batch-flattened col)
  const float LOGMU = logf(1.0f/2048.0f + TINYV);
  float s = 0.0f;
  #pragma unroll
  for (int sl = 0; sl < NSLICE; ++sl) {
    s += colsum[sl*NROWS + c];
    colsum[sl*NROWS + c] = 0.0f;                  // re-zero for next iteration
  }
  v[c] += EPSV * (LOGMU - logf(TINYV + s));
  if (blockIdx.x == 0 && threadIdx.x == 0) {
    const float* ep = errbuf + t*4;
    const float emax = fmaxf(fmaxf(ep[0], ep[1]), fmaxf(ep[2], ep[3]));
    done[t+1] = (emax < THRESHV) ? 1 : 0;         // break AFTER applying this update
  }
}

// ---------------- post1: C_out (fp32, normalized) + cost; reads fp16 C from pi region ----------------
__global__ __launch_bounds__(256) void post1_kernel(
    const __half* __restrict__ Ch, const float* __restrict__ u, const float* __restrict__ v,
    const unsigned int* __restrict__ cmax, float* __restrict__ C_out, float* __restrict__ cost)
{
  const int tid = threadIdx.x, bid = blockIdx.x;
  const int r0 = bid*8, b = bid>>8, jt = tid*8, bcol = b<<11;
  const float scl = 1.0f / __uint_as_float(*cmax);
  __shared__ float red[4];
  float vj[8], ui[8];
  { const float4 a = *(const float4*)(v + bcol + jt);
    const float4 c = *(const float4*)(v + bcol + jt + 4);
    vj[0]=a.x; vj[1]=a.y; vj[2]=a.z; vj[3]=a.w; vj[4]=c.x; vj[5]=c.y; vj[6]=c.z; vj[7]=c.w; }
  { const float4 a = *(const float4*)(u + r0);
    const float4 c = *(const float4*)(u + r0 + 4);
    ui[0]=a.x; ui[1]=a.y; ui[2]=a.z; ui[3]=a.w; ui[4]=c.x; ui[5]=c.y; ui[6]=c.z; ui[7]=c.w; }
  float cp = 0.0f;
  #pragma unroll
  for (int rr = 0; rr < 8; ++rr) {
    const f16x8 ch = *(const f16x8*)(Ch + ((size_t)(r0+rr) << 11) + jt);
    float cn[8];
    #pragma unroll
    for (int k = 0; k < 8; k++) cn[k] = (float)ch[k] * scl;
    float* cdst = C_out + ((size_t)(r0+rr) << 11) + jt;
    *(float4*)(cdst)     = make_float4(cn[0], cn[1], cn[2], cn[3]);
    *(float4*)(cdst + 4) = make_float4(cn[4], cn[5], cn[6], cn[7]);
    #pragma unroll
    for (int k = 0; k < 8; k++) {
      const float p = __expf((ui[rr] + vj[k] - cn[k]) * INVE);
      cp += p * cn[k];
    }
  }
  #pragma unroll
  for (int off = 32; off; off >>= 1) cp += __shfl_xor(cp, off);
  __syncthreads();
  if ((tid & 63) == 0) red[tid >> 6] = cp;
  __syncthreads();
  if (tid == 0) atomicAdd(cost + b, (red[0] + red[1]) + (red[2] + red[3]));
}

// ---------------- post2: pi (overwrites the fp16-C region, now dead) ----------------
__global__ __launch_bounds__(256) void post2_kernel(
    const float* __restrict__ C_out, const float* __restrict__ u, const float* __restrict__ v,
    float* __restrict__ pi)
{
  const int tid = threadIdx.x, bid = blockIdx.x;
  const int r0 = bid*8, b = bid>>8, jt = tid*8, bcol = b<<11;
  float vj[8], ui[8];
  { const float4 a = *(const float4*)(v + bcol + jt);
    const float4 c = *(const float4*)(v + bcol + jt + 4);
    vj[0]=a.x; vj[1]=a.y; vj[2]=a.z; vj[3]=a.w; vj[4]=c.x; vj[5]=c.y; vj[6]=c.z; vj[7]=c.w; }
  { const float4 a = *(const float4*)(u + r0);
    const float4 c = *(const float4*)(u + r0 + 4);
    ui[0]=a.x; ui[1]=a.y; ui[2]=a.z; ui[3]=a.w; ui[4]=c.x; ui[5]=c.y; ui[6]=c.z; ui[7]=c.w; }
  #pragma unroll
  for (int rr = 0; rr < 8; ++rr) {
    const float* csrc = C_out + ((size_t)(r0+rr) << 11) + jt;
    const float4 a = *(const float4*)(csrc);
    const float4 c = *(const float4*)(csrc + 4);
    const float cn[8] = {a.x, a.y, a.z, a.w, c.x, c.y, c.z, c.w};
    float p[8];
    #pragma unroll
    for (int k = 0; k < 8; k++) p[k] = __expf((ui[rr] + vj[k] - cn[k]) * INVE);
    float* pdst = pi + ((size_t)(r0+rr) << 11) + jt;
    *(float4*)(pdst)     = make_float4(p[0], p[1], p[2], p[3]);
    *(float4*)(pdst + 4) = make_float4(p[4], p[5], p[6], p[7]);
  }
}

extern "C" void kernel_launch(void* const* d_in, const int* in_sizes, int n_in,
                              void* d_out, int out_size, void* d_ws, size_t ws_size,
                              hipStream_t stream)
{
  const float* x = (const float*)d_in[0];
  const float* y = (const float*)d_in[1];
  float* out    = (float*)d_out;
  float* cost   = out;                       // (4,)
  float* pi_out = out + 4;                   // (4,2048,2048) fp32
  float* C_out  = out + 4 + NELEM;           // (4,2048,2048) fp32
  __half* Ch = (__half*)pi_out;              // fp16 C parked in pi region (dead before post2)
  __half* xh = (__half*)C_out;               // fp16 x,y parked in C region (dead after gemm)
  __half* yh = xh + (size_t)BSZ * NS * DD;

  float* wsf = (float*)d_ws;                 // ~395 KB of d_ws used
  float* u       = wsf;                      // 8192
  float* v       = u + NROWS;                // 8192
  float* colsum  = v + NROWS;                // NSLICE x 8192
  float* errbuf  = colsum + NSLICE*NROWS;    // 400 (t*4+b)
  int*   done    = (int*)(errbuf + 400);     // 101
  unsigned int* cmax = (unsigned int*)(done + 101);
  float* x2      = (float*)(cmax + 1);       // 8192
  float* y2      = x2 + NROWS;               // 8192

  prep_kernel<<<dim3(4096), dim3(256), 0, stream>>>(x, y, xh, yh, x2, y2, wsf, cost);
  gemm_cost_kernel<<<dim3(16, 16, 4), dim3(256), 0, stream>>>(xh, yh, x2, y2, Ch, cmax);

  for (int t = 0; t < 100; ++t) {
    iter_row_kernel<<<dim3(1024), dim3(256), 0, stream>>>(Ch, u, v, colsum, errbuf, done, cmax, t);
    col_update_kernel<<<dim3(32), dim3(256), 0, stream>>>(v, colsum, errbuf, done, t);
  }

  post1_kernel<<<dim3(1024), dim3(256), 0, stream>>>(Ch, u, v, cmax, C_out, cost);
  post2_kernel<<<dim3(1024), dim3(256), 0, stream>>>(C_out, u, v, pi_out);
}